// Round 1
// baseline (691.637 us; speedup 1.0000x reference)
//
#include <hip/hip_runtime.h>

// Problem constants (from reference)
#define NE_  100000   // entities
#define NB_  1024     // batch
#define DD_  200      // embedding dim = P
#define PP_  224      // padded P (multiple of 32 for 16x16x32 MFMA K)

typedef _Float16 h8 __attribute__((ext_vector_type(8)));
typedef float    fx4 __attribute__((ext_vector_type(4)));

__device__ __forceinline__ float fast_sigmoid(float x) {
    // 1/(1+2^(-x*log2e)); v_exp_f32 + v_rcp_f32, ~1 ulp each — fine at 2e-2 tol
    float e = __builtin_amdgcn_exp2f(-1.44269504088896340736f * x);
    return __builtin_amdgcn_rcpf(1.0f + e);
}

// ---------------------------------------------------------------------------
// Kernel 1: blocks [0,128): h16[b][p] = fp16((r@F0)*(e1@F1)*(t@F3)), fp32 math.
//           blocks [128,136): F2t16[n][k] = fp16(F2[k][n]) (zero-padded).
// Row gathers use wave-uniform addresses -> s_load broadcast; F* column loads
// are lane-coalesced and L2-resident (160 KB each, 128 blocks).
// ---------------------------------------------------------------------------
__global__ __launch_bounds__(256) void prep_kernel(
    const int*   __restrict__ e1_idx, const int* __restrict__ r_idx,
    const int*   __restrict__ t_idx,
    const float* __restrict__ E, const float* __restrict__ R,
    const float* __restrict__ T,
    const float* __restrict__ F0, const float* __restrict__ F1,
    const float* __restrict__ F2, const float* __restrict__ F3,
    _Float16* __restrict__ h16, _Float16* __restrict__ F2t)
{
    const int tid = threadIdx.x;
    const int bid = blockIdx.x;
    if (bid < 128) {
        const int rb = bid * 8;             // 8 batch rows per block
        const float* rrow[8];
        const float* erow[8];
        const float* trow[8];
        #pragma unroll
        for (int i = 0; i < 8; ++i) {       // uniform -> SGPR row bases
            rrow[i] = R + (size_t)r_idx[rb + i]  * DD_;
            erow[i] = E + (size_t)e1_idx[rb + i] * DD_;
            trow[i] = T + (size_t)t_idx[rb + i]  * DD_;
        }
        const int p = tid;                  // output column (rank index)
        float fr[8], fe[8], ft[8];
        #pragma unroll
        for (int i = 0; i < 8; ++i) { fr[i] = 0.f; fe[i] = 0.f; ft[i] = 0.f; }
        if (p < DD_) {
            for (int k = 0; k < DD_; ++k) {
                float f0 = F0[k * DD_ + p];
                float f1 = F1[k * DD_ + p];
                float f3 = F3[k * DD_ + p];
                #pragma unroll
                for (int i = 0; i < 8; ++i) {
                    fr[i] = fmaf(rrow[i][k], f0, fr[i]);
                    fe[i] = fmaf(erow[i][k], f1, fe[i]);
                    ft[i] = fmaf(trow[i][k], f3, ft[i]);
                }
            }
        }
        if (p < PP_) {
            #pragma unroll
            for (int i = 0; i < 8; ++i) {
                float v = (p < DD_) ? fr[i] * fe[i] * ft[i] : 0.0f;
                h16[(size_t)(rb + i) * PP_ + p] = (_Float16)v;
            }
        }
    } else {
        // transpose-convert F2 -> F2t (PP_ x PP_), zeros in pad region
        const int n0 = (bid - 128) * 28;    // 8 blocks x 28 rows = 224
        for (int j = tid; j < 28 * PP_; j += 256) {
            int nl = j / PP_;
            int k  = j - nl * PP_;
            int n  = n0 + nl;
            float v = (n < DD_ && k < DD_) ? F2[k * DD_ + n] : 0.0f;
            F2t[(size_t)n * PP_ + k] = (_Float16)v;
        }
    }
}

// ---------------------------------------------------------------------------
// Kernel 2: FE16 = fp16(E @ F2), M=NE_, N=224(padded), K=224(padded), fp32 acc.
// Block = 64 rows (4 waves x 16), each wave: A-frags straight from global E
// (fp32 -> fp16 in-register), B-frags 16B-contiguous from F2t.
// ---------------------------------------------------------------------------
__global__ __launch_bounds__(256) void fe_kernel(
    const float* __restrict__ E, const _Float16* __restrict__ F2t,
    _Float16* __restrict__ FE)
{
    const int tid  = threadIdx.x;
    const int w    = tid >> 6;
    const int l    = tid & 63;
    const int ln   = l & 15;
    const int quad = l >> 4;
    const int m0   = blockIdx.x * 64;

    int m = m0 + w * 16 + ln;
    if (m >= NE_) m = NE_ - 1;              // clamp loads; stores masked below
    const float* erow = E + (size_t)m * DD_;

    h8 a[7];
    #pragma unroll
    for (int ks = 0; ks < 7; ++ks) {
        const int k = ks * 32 + quad * 8;   // A[m][k..k+7]
        h8 v = {(_Float16)0, (_Float16)0, (_Float16)0, (_Float16)0,
                (_Float16)0, (_Float16)0, (_Float16)0, (_Float16)0};
        if (k < DD_) {                      // k multiple of 8; k<200 => k+8<=200
            fx4 lo = *(const fx4*)(erow + k);
            fx4 hi = *(const fx4*)(erow + k + 4);
            v[0] = (_Float16)lo[0]; v[1] = (_Float16)lo[1];
            v[2] = (_Float16)lo[2]; v[3] = (_Float16)lo[3];
            v[4] = (_Float16)hi[0]; v[5] = (_Float16)hi[1];
            v[6] = (_Float16)hi[2]; v[7] = (_Float16)hi[3];
        }
        a[ks] = v;
    }

    const int mrb = m0 + w * 16 + quad * 4; // C row base (row = quad*4 + r)
    #pragma unroll
    for (int nt = 0; nt < 14; ++nt) {
        fx4 acc = {0.f, 0.f, 0.f, 0.f};
        const _Float16* bp = F2t + (size_t)(nt * 16 + ln) * PP_ + quad * 8;
        #pragma unroll
        for (int ks = 0; ks < 7; ++ks) {
            h8 b = *(const h8*)(bp + ks * 32);
            acc = __builtin_amdgcn_mfma_f32_16x16x32_f16(a[ks], b, acc, 0, 0, 0);
        }
        #pragma unroll
        for (int r = 0; r < 4; ++r) {
            int mr = mrb + r;
            if (mr < NE_)
                FE[(size_t)mr * PP_ + nt * 16 + ln] = (_Float16)acc[r];
        }
    }
}

// ---------------------------------------------------------------------------
// Kernel 3: out = sigmoid(h @ FE^T), M=1024, N=NE_, K=224. Write-bound (410MB).
// Block: 64 entity cols, full M in 8 chunks of 128 rows staged in LDS
// (pitch 232 fp16 -> 2-way bank aliasing = free). FE frags live in 56 VGPRs
// for the whole block (FE read exactly once from HBM).
// Waves: 2(M) x 2(N); wave tile 64x32 = 4x2 C-tiles of 16x16x32 MFMA.
// ---------------------------------------------------------------------------
__global__ __launch_bounds__(256) void score_kernel(
    const _Float16* __restrict__ h16, const _Float16* __restrict__ FE,
    float* __restrict__ out)
{
    __shared__ __align__(16) _Float16 Alds[128 * 232];

    const int tid  = threadIdx.x;
    const int w    = tid >> 6;
    const int l    = tid & 63;
    const int ln   = l & 15;
    const int quad = l >> 4;
    const int wn   = w & 1;                 // N half (0/1 -> +0/+32)
    const int wm   = w >> 1;                // M half within chunk (+0/+64)
    const int n_base = blockIdx.x * 64;

    // Preload B fragments for this block's 64 entities: 2 n-tiles x 7 k-steps
    h8 bfr[2][7];
    #pragma unroll
    for (int nt = 0; nt < 2; ++nt) {
        int n = n_base + wn * 32 + nt * 16 + ln;
        if (n >= NE_) n = NE_ - 1;          // clamp; garbage masked at store
        const _Float16* bp = FE + (size_t)n * PP_ + quad * 8;
        #pragma unroll
        for (int ks = 0; ks < 7; ++ks)
            bfr[nt][ks] = *(const h8*)(bp + ks * 32);
    }

    const int ncol = n_base + wn * 32 + ln;

    for (int c = 0; c < 8; ++c) {
        __syncthreads();                    // protect LDS from previous chunk
        // stage h rows [c*128, c*128+128) -> LDS fp16, pitch 232
        const _Float16* hsrc = h16 + (size_t)(c * 128) * PP_;
        #pragma unroll
        for (int j = 0; j < 14; ++j) {      // 128 rows * 28 vec8 = 3584
            int idx = tid + j * 256;
            int row = idx / 28;
            int kp  = (idx - row * 28) * 8;
            *(h8*)&Alds[row * 232 + kp] = *(const h8*)(hsrc + (size_t)row * PP_ + kp);
        }
        __syncthreads();

        fx4 acc[4][2];
        #pragma unroll
        for (int mt = 0; mt < 4; ++mt)
            #pragma unroll
            for (int nt = 0; nt < 2; ++nt)
                acc[mt][nt] = (fx4){0.f, 0.f, 0.f, 0.f};

        #pragma unroll
        for (int ks = 0; ks < 7; ++ks) {
            h8 af[4];
            #pragma unroll
            for (int mt = 0; mt < 4; ++mt)
                af[mt] = *(const h8*)&Alds[(wm * 64 + mt * 16 + ln) * 232 +
                                           ks * 32 + quad * 8];
            #pragma unroll
            for (int mt = 0; mt < 4; ++mt)
                #pragma unroll
                for (int nt = 0; nt < 2; ++nt)
                    acc[mt][nt] = __builtin_amdgcn_mfma_f32_16x16x32_f16(
                        af[mt], bfr[nt][ks], acc[mt][nt], 0, 0, 0);
        }

        // epilogue: sigmoid + store (C: col=lane&15, row=quad*4+reg)
        const int mbase = c * 128 + wm * 64 + quad * 4;
        #pragma unroll
        for (int nt = 0; nt < 2; ++nt) {
            int n = ncol + nt * 16;
            if (n < NE_) {
                #pragma unroll
                for (int mt = 0; mt < 4; ++mt) {
                    #pragma unroll
                    for (int r = 0; r < 4; ++r) {
                        int m = mbase + mt * 16 + r;
                        out[(size_t)m * NE_ + n] = fast_sigmoid(acc[mt][nt][r]);
                    }
                }
            }
        }
    }
}

// ---------------------------------------------------------------------------
extern "C" void kernel_launch(void* const* d_in, const int* in_sizes, int n_in,
                              void* d_out, int out_size, void* d_ws, size_t ws_size,
                              hipStream_t stream)
{
    const int*   e1_idx = (const int*)  d_in[0];
    const int*   r_idx  = (const int*)  d_in[1];
    const int*   t_idx  = (const int*)  d_in[2];
    const float* E      = (const float*)d_in[3];
    const float* R      = (const float*)d_in[4];
    const float* T      = (const float*)d_in[5];
    const float* F0     = (const float*)d_in[6];
    const float* F1     = (const float*)d_in[7];
    const float* F2     = (const float*)d_in[8];
    const float* F3     = (const float*)d_in[9];
    float* out = (float*)d_out;

    // workspace layout (fp16): FE (NE_ x PP_) | h (NB_ x PP_) | F2t (PP_ x PP_)
    _Float16* FE16 = (_Float16*)d_ws;
    _Float16* h16  = FE16 + (size_t)NE_ * PP_;
    _Float16* F2t  = h16  + (size_t)NB_ * PP_;

    prep_kernel<<<136, 256, 0, stream>>>(e1_idx, r_idx, t_idx, E, R, T,
                                         F0, F1, F2, F3, h16, F2t);

    const int mblocks = (NE_ + 63) / 64;   // 1563
    fe_kernel<<<mblocks, 256, 0, stream>>>(E, F2t, FE16);

    score_kernel<<<mblocks, 256, 0, stream>>>(h16, FE16, out);
}

// Round 2
// 666.284 us; speedup vs baseline: 1.0381x; 1.0381x over previous
//
#include <hip/hip_runtime.h>

// Problem constants (from reference)
#define NE_  100000   // entities
#define NB_  1024     // batch
#define DD_  200      // embedding dim = P
#define PP_  224      // padded P (multiple of 32)

typedef _Float16 h8  __attribute__((ext_vector_type(8)));
typedef float    fx4 __attribute__((ext_vector_type(4)));
typedef float    fx16 __attribute__((ext_vector_type(16)));

__device__ __forceinline__ float fast_sigmoid(float x) {
    float e = __builtin_amdgcn_exp2f(-1.44269504088896340736f * x);
    return __builtin_amdgcn_rcpf(1.0f + e);
}

// ---------------------------------------------------------------------------
// Kernel 1: blocks [0,128): h16[b][p] = fp16((r@F0)*(e1@F1)*(t@F3)), fp32 math.
//           blocks [128,136): F2t16[n][k] = fp16(F2[k][n]) (zero-padded).
// ---------------------------------------------------------------------------
__global__ __launch_bounds__(256) void prep_kernel(
    const int*   __restrict__ e1_idx, const int* __restrict__ r_idx,
    const int*   __restrict__ t_idx,
    const float* __restrict__ E, const float* __restrict__ R,
    const float* __restrict__ T,
    const float* __restrict__ F0, const float* __restrict__ F1,
    const float* __restrict__ F2, const float* __restrict__ F3,
    _Float16* __restrict__ h16, _Float16* __restrict__ F2t)
{
    const int tid = threadIdx.x;
    const int bid = blockIdx.x;
    if (bid < 128) {
        const int rb = bid * 8;             // 8 batch rows per block
        const float* rrow[8];
        const float* erow[8];
        const float* trow[8];
        #pragma unroll
        for (int i = 0; i < 8; ++i) {       // uniform -> SGPR row bases
            rrow[i] = R + (size_t)r_idx[rb + i]  * DD_;
            erow[i] = E + (size_t)e1_idx[rb + i] * DD_;
            trow[i] = T + (size_t)t_idx[rb + i]  * DD_;
        }
        const int p = tid;                  // output column (rank index)
        float fr[8], fe[8], ft[8];
        #pragma unroll
        for (int i = 0; i < 8; ++i) { fr[i] = 0.f; fe[i] = 0.f; ft[i] = 0.f; }
        if (p < DD_) {
            for (int k = 0; k < DD_; ++k) {
                float f0 = F0[k * DD_ + p];
                float f1 = F1[k * DD_ + p];
                float f3 = F3[k * DD_ + p];
                #pragma unroll
                for (int i = 0; i < 8; ++i) {
                    fr[i] = fmaf(rrow[i][k], f0, fr[i]);
                    fe[i] = fmaf(erow[i][k], f1, fe[i]);
                    ft[i] = fmaf(trow[i][k], f3, ft[i]);
                }
            }
        }
        if (p < PP_) {
            #pragma unroll
            for (int i = 0; i < 8; ++i) {
                float v = (p < DD_) ? fr[i] * fe[i] * ft[i] : 0.0f;
                h16[(size_t)(rb + i) * PP_ + p] = (_Float16)v;
            }
        }
    } else {
        const int n0 = (bid - 128) * 28;    // 8 blocks x 28 rows = 224
        for (int j = tid; j < 28 * PP_; j += 256) {
            int nl = j / PP_;
            int k  = j - nl * PP_;
            int n  = n0 + nl;
            float v = (n < DD_ && k < DD_) ? F2[k * DD_ + n] : 0.0f;
            F2t[(size_t)n * PP_ + k] = (_Float16)v;
        }
    }
}

// ---------------------------------------------------------------------------
// Kernel 2: FE16 = fp16(E @ F2), M=NE_, N=224(padded), K=224(padded), fp32 acc.
// (unchanged from R1 — passed, estimated minor share of total)
// ---------------------------------------------------------------------------
__global__ __launch_bounds__(256) void fe_kernel(
    const float* __restrict__ E, const _Float16* __restrict__ F2t,
    _Float16* __restrict__ FE)
{
    const int tid  = threadIdx.x;
    const int w    = tid >> 6;
    const int l    = tid & 63;
    const int ln   = l & 15;
    const int quad = l >> 4;
    const int m0   = blockIdx.x * 64;

    int m = m0 + w * 16 + ln;
    if (m >= NE_) m = NE_ - 1;
    const float* erow = E + (size_t)m * DD_;

    h8 a[7];
    #pragma unroll
    for (int ks = 0; ks < 7; ++ks) {
        const int k = ks * 32 + quad * 8;
        h8 v = {(_Float16)0, (_Float16)0, (_Float16)0, (_Float16)0,
                (_Float16)0, (_Float16)0, (_Float16)0, (_Float16)0};
        if (k < DD_) {
            fx4 lo = *(const fx4*)(erow + k);
            fx4 hi = *(const fx4*)(erow + k + 4);
            v[0] = (_Float16)lo[0]; v[1] = (_Float16)lo[1];
            v[2] = (_Float16)lo[2]; v[3] = (_Float16)lo[3];
            v[4] = (_Float16)hi[0]; v[5] = (_Float16)hi[1];
            v[6] = (_Float16)hi[2]; v[7] = (_Float16)hi[3];
        }
        a[ks] = v;
    }

    const int mrb = m0 + w * 16 + quad * 4;
    #pragma unroll
    for (int nt = 0; nt < 14; ++nt) {
        fx4 acc = {0.f, 0.f, 0.f, 0.f};
        const _Float16* bp = F2t + (size_t)(nt * 16 + ln) * PP_ + quad * 8;
        #pragma unroll
        for (int ks = 0; ks < 7; ++ks) {
            h8 b = *(const h8*)(bp + ks * 32);
            acc = __builtin_amdgcn_mfma_f32_16x16x32_f16(a[ks], b, acc, 0, 0, 0);
        }
        #pragma unroll
        for (int r = 0; r < 4; ++r) {
            int mr = mrb + r;
            if (mr < NE_)
                FE[(size_t)mr * PP_ + nt * 16 + ln] = (_Float16)acc[r];
        }
    }
}

// ---------------------------------------------------------------------------
// Kernel 3 (REWRITTEN): out = sigmoid(h @ FE^T) via mfma_f32_32x32x16_f16.
// Block: 64 entity cols x full M=1024 in 16 chunks of 64 rows.
// LDS 64x232 fp16 = 29.7 KB -> 4 blocks/CU (with launch_bounds(256,4)).
// Waves: wm = row half (32), wn = col half (32); 1 C-tile (32x32) per wave.
// C layout: col=lane&31 -> store instr = 2 x 128B full-line segments.
// B-frags (14 ks x 4 VGPR = 56) held in registers for the whole block.
// ---------------------------------------------------------------------------
__global__ __launch_bounds__(256, 4) void score_kernel(
    const _Float16* __restrict__ h16, const _Float16* __restrict__ FE,
    float* __restrict__ out)
{
    __shared__ __align__(16) _Float16 Alds[64 * 232];  // pitch 232 = 29x16B, odd -> conflict-free b128

    const int tid = threadIdx.x;
    const int w   = tid >> 6;
    const int l   = tid & 63;
    const int l31 = l & 31;
    const int lh  = l >> 5;
    const int wm  = w & 1;                  // row half within 64-row chunk
    const int wn  = w >> 1;                 // col half within 64-col block tile
    const int nb  = blockIdx.x * 64;

    // Preload B fragments (FE rows for this wave's 32 entity cols), 14 k-steps
    h8 bfr[14];
    {
        int n = nb + wn * 32 + l31;
        if (n >= NE_) n = NE_ - 1;          // clamp loads; stores masked below
        const _Float16* bp = FE + (size_t)n * PP_ + lh * 8;
        #pragma unroll
        for (int ks = 0; ks < 14; ++ks)
            bfr[ks] = *(const h8*)(bp + ks * 16);
    }

    const int ncol = nb + wn * 32 + l31;
    const bool nok = (ncol < NE_);
    // staging assignment: 4 threads per row, 7 x 16B each
    const int srow = tid >> 2;              // 0..63
    const int scol = (tid & 3) * 8;         // element offset, +32 per j

    for (int c = 0; c < 16; ++c) {
        __syncthreads();                    // protect LDS from previous chunk
        const _Float16* hsrc = h16 + (size_t)(c * 64) * PP_;
        #pragma unroll
        for (int j = 0; j < 7; ++j)
            *(h8*)&Alds[srow * 232 + scol + j * 32] =
                *(const h8*)(hsrc + (size_t)srow * PP_ + scol + j * 32);
        __syncthreads();

        fx16 acc;
        #pragma unroll
        for (int i = 0; i < 16; ++i) acc[i] = 0.0f;

        #pragma unroll
        for (int ks = 0; ks < 14; ++ks) {
            // A[m=lane&31][k=ks*16 + lh*8 + j]
            h8 a = *(const h8*)&Alds[(wm * 32 + l31) * 232 + ks * 16 + lh * 8];
            acc = __builtin_amdgcn_mfma_f32_32x32x16_f16(a, bfr[ks], acc, 0, 0, 0);
        }

        // epilogue: sigmoid + store. row=(reg&3)+8*(reg>>2)+4*lh, col=lane&31
        if (nok) {
            const int mb = c * 64 + wm * 32 + lh * 4;
            #pragma unroll
            for (int r = 0; r < 16; ++r) {
                int m = mb + (r & 3) + 8 * (r >> 2);
                out[(size_t)m * NE_ + ncol] = fast_sigmoid(acc[r]);
            }
        }
    }
}

// ---------------------------------------------------------------------------
extern "C" void kernel_launch(void* const* d_in, const int* in_sizes, int n_in,
                              void* d_out, int out_size, void* d_ws, size_t ws_size,
                              hipStream_t stream)
{
    const int*   e1_idx = (const int*)  d_in[0];
    const int*   r_idx  = (const int*)  d_in[1];
    const int*   t_idx  = (const int*)  d_in[2];
    const float* E      = (const float*)d_in[3];
    const float* R      = (const float*)d_in[4];
    const float* T      = (const float*)d_in[5];
    const float* F0     = (const float*)d_in[6];
    const float* F1     = (const float*)d_in[7];
    const float* F2     = (const float*)d_in[8];
    const float* F3     = (const float*)d_in[9];
    float* out = (float*)d_out;

    // workspace layout (fp16): FE (NE_ x PP_) | h (NB_ x PP_) | F2t (PP_ x PP_)
    _Float16* FE16 = (_Float16*)d_ws;
    _Float16* h16  = FE16 + (size_t)NE_ * PP_;
    _Float16* F2t  = h16  + (size_t)NB_ * PP_;

    prep_kernel<<<136, 256, 0, stream>>>(e1_idx, r_idx, t_idx, E, R, T,
                                         F0, F1, F2, F3, h16, F2t);

    const int mblocks = (NE_ + 63) / 64;   // 1563
    fe_kernel<<<mblocks, 256, 0, stream>>>(E, F2t, FE16);

    score_kernel<<<mblocks, 256, 0, stream>>>(h16, FE16, out);
}